// Round 11
// baseline (149.736 us; speedup 1.0000x reference)
//
#include <hip/hip_runtime.h>
#include <hip/hip_bf16.h>

#define N_LATENT 64
#define N_OUT    64

__device__ __forceinline__ float rl(float v, int l) {
    return __int_as_float(__builtin_amdgcn_readlane(__float_as_int(v), l));
}

// One block (256 thr = 4 waves) per sample id s. Waves scan the 256 KB sid
// array (L2-broadcast, int4+ballot) and enqueue matching rows into a static
// 8-slot shift-register queue. On flush, ONE pass over A's 64 rows feeds 8
// rows' FMAs (A L1-traffic amortized 8x vs round-7's per-row re-read, which
// was the 49us bottleneck: VGPR=40 proved A never stayed in registers).
__global__ __launch_bounds__(256, 4) void decoder_scan_kernel(
    const float* __restrict__ u,
    const int*   __restrict__ sid,
    const float* __restrict__ amat,
    const float* __restrict__ offsets,
    float*       __restrict__ out,
    int batch)
{
    const int s      = blockIdx.x;          // sample id
    const int lane   = threadIdx.x & 63;    // output column
    const int wave   = threadIdx.x >> 6;    // 0..3
    const int nwaves = blockDim.x >> 6;     // 4

    const float* __restrict__ A = amat + (size_t)s * (N_LATENT * N_OUT);
    const float off = offsets[(size_t)s * N_OUT + lane];

    // wave-uniform row queue; init 0 so stale slots still give valid addresses
    int q0=0,q1=0,q2=0,q3=0,q4=0,q5=0,q6=0,q7=0;
    int qn = 0;

    // Process slots q0..q[n-1]. One A pass (64 loads) serves up to 8 rows.
    auto flush = [&](int n) {
        float v0 = u[(size_t)q0 * N_LATENT + lane];
        float v1 = u[(size_t)q1 * N_LATENT + lane];
        float v2 = u[(size_t)q2 * N_LATENT + lane];
        float v3 = u[(size_t)q3 * N_LATENT + lane];
        float v4 = u[(size_t)q4 * N_LATENT + lane];
        float v5 = u[(size_t)q5 * N_LATENT + lane];
        float v6 = u[(size_t)q6 * N_LATENT + lane];
        float v7 = u[(size_t)q7 * N_LATENT + lane];
        float a0=off,a1=off,a2=off,a3=off,a4=off,a5=off,a6=off,a7=off;
#pragma unroll
        for (int d = 0; d < N_LATENT; ++d) {
            const float ad = A[d * N_OUT + lane];
            a0 = fmaf(rl(v0, d), ad, a0);
            a1 = fmaf(rl(v1, d), ad, a1);
            a2 = fmaf(rl(v2, d), ad, a2);
            a3 = fmaf(rl(v3, d), ad, a3);
            a4 = fmaf(rl(v4, d), ad, a4);
            a5 = fmaf(rl(v5, d), ad, a5);
            a6 = fmaf(rl(v6, d), ad, a6);
            a7 = fmaf(rl(v7, d), ad, a7);
        }
        if (n > 0) out[(size_t)q0 * N_OUT + lane] = v0 + a0;
        if (n > 1) out[(size_t)q1 * N_OUT + lane] = v1 + a1;
        if (n > 2) out[(size_t)q2 * N_OUT + lane] = v2 + a2;
        if (n > 3) out[(size_t)q3 * N_OUT + lane] = v3 + a3;
        if (n > 4) out[(size_t)q4 * N_OUT + lane] = v4 + a4;
        if (n > 5) out[(size_t)q5 * N_OUT + lane] = v5 + a5;
        if (n > 6) out[(size_t)q6 * N_OUT + lane] = v6 + a6;
        if (n > 7) out[(size_t)q7 * N_OUT + lane] = v7 + a7;
    };

    // ---- scan sid in int4 with 1-deep prefetch ----
    const int4* __restrict__ sid4 = (const int4*)sid;
    const int n4       = batch >> 2;                        // batch % 4 == 0
    const int per_wave = (n4 + nwaves - 1) / nwaves;
    const int begin    = wave * per_wave;
    const int end      = (begin + per_wave < n4) ? (begin + per_wave) : n4;
    if (begin >= end) return;

    int cfirst = begin + lane;
    int4 v = sid4[(cfirst < n4) ? cfirst : (n4 - 1)];
    if (cfirst >= end) v = make_int4(-1, -1, -1, -1);

    for (int c0 = begin; c0 < end; c0 += 64) {
        const int cn = c0 + 64 + lane;
        int4 vn = sid4[(cn < n4) ? cn : (n4 - 1)];
        if (cn >= end) vn = make_int4(-1, -1, -1, -1);

        unsigned long long m[4];
        m[0] = __ballot(v.x == s);
        m[1] = __ballot(v.y == s);
        m[2] = __ballot(v.z == s);
        m[3] = __ballot(v.w == s);

#pragma unroll
        for (int e = 0; e < 4; ++e) {
            unsigned long long mm = m[e];
            while (mm) {                          // wave-uniform loop
                const int j = __builtin_ctzll(mm);
                mm &= mm - 1;
                int b = 4 * (c0 + j) + e;         // matching row (uniform)
                b = __builtin_amdgcn_readfirstlane(b);
                q7=q6; q6=q5; q5=q4; q4=q3; q3=q2; q2=q1; q1=q0; q0=b;
                if (++qn == 8) { flush(8); qn = 0; }
            }
        }
        v = vn;
    }
    if (qn > 0) flush(qn);                        // masked tail flush
}

extern "C" void kernel_launch(void* const* d_in, const int* in_sizes, int n_in,
                              void* d_out, int out_size, void* d_ws, size_t ws_size,
                              hipStream_t stream)
{
    const float* u       = (const float*)d_in[0];
    const int*   sid     = (const int*)d_in[1];
    const float* amat    = (const float*)d_in[2];
    const float* offsets = (const float*)d_in[3];
    float*       out     = (float*)d_out;

    const int batch    = in_sizes[0] / N_LATENT;            // 65536
    const int n_sample = in_sizes[2] / (N_LATENT * N_OUT);  // 1000

    decoder_scan_kernel<<<n_sample, 256, 0, stream>>>(
        u, sid, amat, offsets, out, batch);
}

// Round 12
// 73.743 us; speedup vs baseline: 2.0305x; 2.0305x over previous
//
#include <hip/hip_runtime.h>
#include <hip/hip_bf16.h>

#define N_LATENT 64
#define N_OUT    64

__device__ __forceinline__ float rl(float v, int l) {
    return __int_as_float(__builtin_amdgcn_readlane(__float_as_int(v), l));
}

// Flush up to 8 queued rows with ONE pass over A (amortizes the 64 A-loads
// across 8 rows). ALL state passed BY VALUE -> no closure, nothing can be
// forced to scratch (round-11 failure: by-ref lambda captures gave every
// queue register a scratch home -> 105 MB of spill traffic, 150 us).
// q_i are wave-uniform (SGPRs). Stale slots (i >= n) compute garbage rows
// harmlessly; their stores are masked by the uniform n.
__device__ __forceinline__ void flush_rows(
    const float* __restrict__ u, const float* __restrict__ A,
    float off, int lane, float* __restrict__ out,
    int q0, int q1, int q2, int q3, int q4, int q5, int q6, int q7, int n)
{
    float v0 = u[(size_t)q0 * N_LATENT + lane];
    float v1 = u[(size_t)q1 * N_LATENT + lane];
    float v2 = u[(size_t)q2 * N_LATENT + lane];
    float v3 = u[(size_t)q3 * N_LATENT + lane];
    float v4 = u[(size_t)q4 * N_LATENT + lane];
    float v5 = u[(size_t)q5 * N_LATENT + lane];
    float v6 = u[(size_t)q6 * N_LATENT + lane];
    float v7 = u[(size_t)q7 * N_LATENT + lane];
    float a0 = off, a1 = off, a2 = off, a3 = off;
    float a4 = off, a5 = off, a6 = off, a7 = off;
#pragma unroll
    for (int d = 0; d < N_LATENT; ++d) {
        const float ad = A[d * N_OUT + lane];
        a0 = fmaf(rl(v0, d), ad, a0);
        a1 = fmaf(rl(v1, d), ad, a1);
        a2 = fmaf(rl(v2, d), ad, a2);
        a3 = fmaf(rl(v3, d), ad, a3);
        a4 = fmaf(rl(v4, d), ad, a4);
        a5 = fmaf(rl(v5, d), ad, a5);
        a6 = fmaf(rl(v6, d), ad, a6);
        a7 = fmaf(rl(v7, d), ad, a7);
    }
    /* q0 is newest; valid slots are q0..q(n-1) */
    if (n > 0) out[(size_t)q0 * N_OUT + lane] = v0 + a0;
    if (n > 1) out[(size_t)q1 * N_OUT + lane] = v1 + a1;
    if (n > 2) out[(size_t)q2 * N_OUT + lane] = v2 + a2;
    if (n > 3) out[(size_t)q3 * N_OUT + lane] = v3 + a3;
    if (n > 4) out[(size_t)q4 * N_OUT + lane] = v4 + a4;
    if (n > 5) out[(size_t)q5 * N_OUT + lane] = v5 + a5;
    if (n > 6) out[(size_t)q6 * N_OUT + lane] = v6 + a6;
    if (n > 7) out[(size_t)q7 * N_OUT + lane] = v7 + a7;
}

// One block (256 thr = 4 waves) per sample id s. Waves scan the 256 KB sid
// array (L2-broadcast, int4+ballot), enqueue matching rows into an SGPR
// shift-register queue, and flush 8 rows per A pass.
__global__ __launch_bounds__(256) void decoder_scan_kernel(
    const float* __restrict__ u,
    const int*   __restrict__ sid,
    const float* __restrict__ amat,
    const float* __restrict__ offsets,
    float*       __restrict__ out,
    int batch)
{
    const int s      = blockIdx.x;          // sample id
    const int lane   = threadIdx.x & 63;    // output column
    const int wave   = threadIdx.x >> 6;    // 0..3
    const int nwaves = blockDim.x >> 6;     // 4

    const float* __restrict__ A = amat + (size_t)s * (N_LATENT * N_OUT);
    const float off = offsets[(size_t)s * N_OUT + lane];

    // wave-uniform row queue (SGPRs via readfirstlane); 0-init = valid addr
    int q0=0,q1=0,q2=0,q3=0,q4=0,q5=0,q6=0,q7=0;
    int qn = 0;

    const int4* __restrict__ sid4 = (const int4*)sid;
    const int n4       = batch >> 2;                        // batch % 4 == 0
    const int per_wave = (n4 + nwaves - 1) / nwaves;
    const int begin    = wave * per_wave;
    const int end      = (begin + per_wave < n4) ? (begin + per_wave) : n4;
    if (begin >= end) return;

    for (int c0 = begin; c0 < end; c0 += 64) {
        const int c = c0 + lane;
        int4 v;
        if (c < end) v = sid4[c];
        else         v = make_int4(-1, -1, -1, -1);

        unsigned long long m[4];
        m[0] = __ballot(v.x == s);
        m[1] = __ballot(v.y == s);
        m[2] = __ballot(v.z == s);
        m[3] = __ballot(v.w == s);

#pragma unroll
        for (int e = 0; e < 4; ++e) {
            unsigned long long mm = m[e];
            while (mm) {                          // wave-uniform loop
                const int j = __builtin_ctzll(mm);
                mm &= mm - 1;
                const int b = __builtin_amdgcn_readfirstlane(4 * (c0 + j) + e);
                q7=q6; q6=q5; q5=q4; q4=q3; q3=q2; q2=q1; q1=q0; q0=b;
                if (++qn == 8) {
                    flush_rows(u, A, off, lane, out,
                               q0,q1,q2,q3,q4,q5,q6,q7, 8);
                    qn = 0;
                }
            }
        }
    }
    if (qn > 0) {
        flush_rows(u, A, off, lane, out, q0,q1,q2,q3,q4,q5,q6,q7, qn);
    }
}

extern "C" void kernel_launch(void* const* d_in, const int* in_sizes, int n_in,
                              void* d_out, int out_size, void* d_ws, size_t ws_size,
                              hipStream_t stream)
{
    const float* u       = (const float*)d_in[0];
    const int*   sid     = (const int*)d_in[1];
    const float* amat    = (const float*)d_in[2];
    const float* offsets = (const float*)d_in[3];
    float*       out     = (float*)d_out;

    const int batch    = in_sizes[0] / N_LATENT;            // 65536
    const int n_sample = in_sizes[2] / (N_LATENT * N_OUT);  // 1000

    decoder_scan_kernel<<<n_sample, 256, 0, stream>>>(
        u, sid, amat, offsets, out, batch);
}

// Round 13
// 71.881 us; speedup vs baseline: 2.0831x; 1.0259x over previous
//
#include <hip/hip_runtime.h>
#include <hip/hip_bf16.h>

#define N_LATENT 64
#define N_OUT    64

__device__ __forceinline__ float rl(float v, int l) {
    return __int_as_float(__builtin_amdgcn_readlane(__float_as_int(v), l));
}

// Flush up to 8 queued rows with ONE pass over A (amortizes 64 A-loads across
// 8 rows -> A L1-traffic 8x down vs per-row re-read). ALL state by value --
// no closure, nothing spills (round-11 lesson). q_i wave-uniform; stale slots
// compute garbage harmlessly, stores masked by uniform n.
__device__ __forceinline__ void flush_rows(
    const float* __restrict__ u, const float* __restrict__ A,
    float off, int lane, float* __restrict__ out,
    int q0, int q1, int q2, int q3, int q4, int q5, int q6, int q7, int n)
{
    float v0 = u[(size_t)q0 * N_LATENT + lane];
    float v1 = u[(size_t)q1 * N_LATENT + lane];
    float v2 = u[(size_t)q2 * N_LATENT + lane];
    float v3 = u[(size_t)q3 * N_LATENT + lane];
    float v4 = u[(size_t)q4 * N_LATENT + lane];
    float v5 = u[(size_t)q5 * N_LATENT + lane];
    float v6 = u[(size_t)q6 * N_LATENT + lane];
    float v7 = u[(size_t)q7 * N_LATENT + lane];
    float a0 = off, a1 = off, a2 = off, a3 = off;
    float a4 = off, a5 = off, a6 = off, a7 = off;
#pragma unroll
    for (int d = 0; d < N_LATENT; ++d) {
        const float ad = A[d * N_OUT + lane];
        a0 = fmaf(rl(v0, d), ad, a0);
        a1 = fmaf(rl(v1, d), ad, a1);
        a2 = fmaf(rl(v2, d), ad, a2);
        a3 = fmaf(rl(v3, d), ad, a3);
        a4 = fmaf(rl(v4, d), ad, a4);
        a5 = fmaf(rl(v5, d), ad, a5);
        a6 = fmaf(rl(v6, d), ad, a6);
        a7 = fmaf(rl(v7, d), ad, a7);
    }
    if (n > 0) out[(size_t)q0 * N_OUT + lane] = v0 + a0;
    if (n > 1) out[(size_t)q1 * N_OUT + lane] = v1 + a1;
    if (n > 2) out[(size_t)q2 * N_OUT + lane] = v2 + a2;
    if (n > 3) out[(size_t)q3 * N_OUT + lane] = v3 + a3;
    if (n > 4) out[(size_t)q4 * N_OUT + lane] = v4 + a4;
    if (n > 5) out[(size_t)q5 * N_OUT + lane] = v5 + a5;
    if (n > 6) out[(size_t)q6 * N_OUT + lane] = v6 + a6;
    if (n > 7) out[(size_t)q7 * N_OUT + lane] = v7 + a7;
}

// Enqueue matches of one ballot mask; flush every 8 rows. Macro, not lambda
// (round-11: non-inlined by-ref lambda spilled everything to scratch).
#define DRAIN(MASK, ELEM, BASE)                                               \
    {                                                                         \
        unsigned long long mm = (MASK);                                       \
        while (mm) {                                                          \
            int j = __builtin_ctzll(mm); mm &= mm - 1;                        \
            int b = __builtin_amdgcn_readfirstlane(4 * ((BASE) + j) + (ELEM));\
            q7=q6; q6=q5; q5=q4; q4=q3; q3=q2; q2=q1; q1=q0; q0=b;            \
            if (++qn == 8) {                                                  \
                flush_rows(u, A, off, lane, out,                              \
                           q0,q1,q2,q3,q4,q5,q6,q7, 8);                       \
                qn = 0;                                                       \
            }                                                                 \
        }                                                                     \
    }

#define PROCESS4(VV, BASE)                                                    \
    {                                                                         \
        unsigned long long b0 = __ballot((VV).x == s);                        \
        unsigned long long b1 = __ballot((VV).y == s);                        \
        unsigned long long b2 = __ballot((VV).z == s);                        \
        unsigned long long b3 = __ballot((VV).w == s);                        \
        DRAIN(b0, 0, BASE); DRAIN(b1, 1, BASE);                               \
        DRAIN(b2, 2, BASE); DRAIN(b3, 3, BASE);                               \
    }

// One block (512 thr = 8 waves) per sample id s. Each wave scans 1/8 of the
// 256 KB sid array, TWO int4 loads per iteration, 1-deep prefetch so L2
// latency pipelines (round-12 failure: serial un-prefetched scan, 64 iters x
// ~300cy = 73us). Matching rows -> SGPR queue -> 8 rows per A pass.
__global__ __launch_bounds__(512) void decoder_scan_kernel(
    const float* __restrict__ u,
    const int*   __restrict__ sid,
    const float* __restrict__ amat,
    const float* __restrict__ offsets,
    float*       __restrict__ out,
    int batch)
{
    const int s      = blockIdx.x;          // sample id
    const int lane   = threadIdx.x & 63;    // output column
    const int wave   = threadIdx.x >> 6;    // 0..7
    const int nwaves = blockDim.x >> 6;     // 8

    const float* __restrict__ u_  = u;
    const float* __restrict__ A = amat + (size_t)s * (N_LATENT * N_OUT);
    const float off = offsets[(size_t)s * N_OUT + lane];

    int q0=0,q1=0,q2=0,q3=0,q4=0,q5=0,q6=0,q7=0;
    int qn = 0;

    const int4* __restrict__ sid4 = (const int4*)sid;
    const int n4       = batch >> 2;                        // 16384
    const int per_wave = (n4 + nwaves - 1) / nwaves;        // 2048
    const int begin    = wave * per_wave;
    const int end      = (begin + per_wave < n4) ? (begin + per_wave) : n4;
    if (begin >= end) return;

    // prologue: first pair
    const int ca = begin + lane;
    const int cb = begin + 64 + lane;
    int4 va = sid4[(ca < n4) ? ca : (n4 - 1)];
    int4 vb = sid4[(cb < n4) ? cb : (n4 - 1)];
    if (ca >= end) va = make_int4(-1,-1,-1,-1);
    if (cb >= end) vb = make_int4(-1,-1,-1,-1);

    for (int c0 = begin; c0 < end; c0 += 128) {
        // prefetch next pair (two independent loads, wait deferred to use)
        const int na = c0 + 128 + lane;
        const int nb = c0 + 192 + lane;
        int4 pa = sid4[(na < n4) ? na : (n4 - 1)];
        int4 pb = sid4[(nb < n4) ? nb : (n4 - 1)];
        if (na >= end) pa = make_int4(-1,-1,-1,-1);
        if (nb >= end) pb = make_int4(-1,-1,-1,-1);

        PROCESS4(va, c0 + lane);
        PROCESS4(vb, c0 + 64 + lane);

        va = pa; vb = pb;
    }
    if (qn > 0) {
        flush_rows(u, A, off, lane, out, q0,q1,q2,q3,q4,q5,q6,q7, qn);
    }
    (void)u_;
}

extern "C" void kernel_launch(void* const* d_in, const int* in_sizes, int n_in,
                              void* d_out, int out_size, void* d_ws, size_t ws_size,
                              hipStream_t stream)
{
    const float* u       = (const float*)d_in[0];
    const int*   sid     = (const int*)d_in[1];
    const float* amat    = (const float*)d_in[2];
    const float* offsets = (const float*)d_in[3];
    float*       out     = (float*)d_out;

    const int batch    = in_sizes[0] / N_LATENT;            // 65536
    const int n_sample = in_sizes[2] / (N_LATENT * N_OUT);  // 1000

    decoder_scan_kernel<<<n_sample, 512, 0, stream>>>(
        u, sid, amat, offsets, out, batch);
}

// Round 14
// 55.081 us; speedup vs baseline: 2.7185x; 1.3050x over previous
//
#include <hip/hip_runtime.h>
#include <hip/hip_bf16.h>

#define N_LATENT 64
#define N_OUT    64
#define SPLIT    4      // chunks per sample -> grid = 1000*SPLIT blocks
#define LIST_CAP 512    // chunk match capacity (mean 16.4, sd 4 -> 122 sigma)

__device__ __forceinline__ float rl(float v, int l) {
    return __int_as_float(__builtin_amdgcn_readlane(__float_as_int(v), l));
}

// Block = (sample s, chunk c). Phase 0: A[s] -> LDS. Phase 1: scan this
// chunk's 16K sids, append matching rows to an LDS list (LDS atomics).
// Phase 2: waves pull 4-row groups off the list; one pass over A-LDS per
// group amortizes A reads 4x; u broadcast via readlane.
// Rounds 12/13 failed on serial scan->SGPR-queue->flush on one wave at 16%
// occupancy; this decouples phases and uses 4000 small blocks so TLP hides
// the L2 scan latency.
__global__ __launch_bounds__(256) void decoder_kernel(
    const float* __restrict__ u,
    const int*   __restrict__ sid,
    const float* __restrict__ amat,
    const float* __restrict__ offsets,
    float*       __restrict__ out,
    int batch)
{
    __shared__ float Alds[N_LATENT * N_OUT];   // 16 KB
    __shared__ int   list[LIST_CAP];           // 2 KB
    __shared__ int   cnt;

    const int tid   = threadIdx.x;
    const int s     = blockIdx.x >> 2;         // sample id
    const int chunk = blockIdx.x & (SPLIT - 1);

    // ---- Phase 0: stage A into LDS (1024 float4, 4 per thread) ----
    {
        const float4* __restrict__ A4 =
            (const float4*)(amat + (size_t)s * (N_LATENT * N_OUT));
        float4* Alds4 = (float4*)Alds;
#pragma unroll
        for (int k = 0; k < 4; ++k)
            Alds4[k * 256 + tid] = A4[k * 256 + tid];
    }
    if (tid == 0) cnt = 0;
    __syncthreads();

    // ---- Phase 1: scan chunk, append matches to LDS list ----
    {
        const int4* __restrict__ sid4 = (const int4*)sid;
        const int n4    = batch >> 2;                    // 16384
        const int c_per = n4 / SPLIT;                    // 4096
        const int cbeg  = chunk * c_per;
        const int cend  = (chunk == SPLIT - 1) ? n4 : (cbeg + c_per);

        for (int i = cbeg + tid; i < cend; i += 256) {
            const int4 v = sid4[i];
            const int rbase = 4 * i;
            if (v.x == s) { int p = atomicAdd(&cnt, 1); if (p < LIST_CAP) list[p] = rbase;     }
            if (v.y == s) { int p = atomicAdd(&cnt, 1); if (p < LIST_CAP) list[p] = rbase + 1; }
            if (v.z == s) { int p = atomicAdd(&cnt, 1); if (p < LIST_CAP) list[p] = rbase + 2; }
            if (v.w == s) { int p = atomicAdd(&cnt, 1); if (p < LIST_CAP) list[p] = rbase + 3; }
        }
    }
    __syncthreads();

    // ---- Phase 2: compute rows in 4-row groups per wave ----
    const int n    = (cnt < LIST_CAP) ? cnt : LIST_CAP;
    const int lane = tid & 63;
    const int wave = tid >> 6;                 // 0..3

    const float off = offsets[(size_t)s * N_OUT + lane];

    for (int g0 = wave * 4; g0 < n; g0 += 16) {
        const int m  = n - g0;                 // >= 1
        const int b0 = list[g0];
        const int b1 = list[(m > 1) ? g0 + 1 : g0];
        const int b2 = list[(m > 2) ? g0 + 2 : g0];
        const int b3 = list[(m > 3) ? g0 + 3 : g0];

        const float v0 = u[(size_t)b0 * N_LATENT + lane];
        const float v1 = u[(size_t)b1 * N_LATENT + lane];
        const float v2 = u[(size_t)b2 * N_LATENT + lane];
        const float v3 = u[(size_t)b3 * N_LATENT + lane];

        float a0 = off, a1 = off, a2 = off, a3 = off;
#pragma unroll
        for (int d = 0; d < N_LATENT; ++d) {
            const float ad = Alds[d * N_OUT + lane];   // 2-way bank alias: free
            a0 = fmaf(rl(v0, d), ad, a0);
            a1 = fmaf(rl(v1, d), ad, a1);
            a2 = fmaf(rl(v2, d), ad, a2);
            a3 = fmaf(rl(v3, d), ad, a3);
        }

        out[(size_t)b0 * N_OUT + lane] = v0 + a0;
        if (m > 1) out[(size_t)b1 * N_OUT + lane] = v1 + a1;
        if (m > 2) out[(size_t)b2 * N_OUT + lane] = v2 + a2;
        if (m > 3) out[(size_t)b3 * N_OUT + lane] = v3 + a3;
    }
}

extern "C" void kernel_launch(void* const* d_in, const int* in_sizes, int n_in,
                              void* d_out, int out_size, void* d_ws, size_t ws_size,
                              hipStream_t stream)
{
    const float* u       = (const float*)d_in[0];
    const int*   sid     = (const int*)d_in[1];
    const float* amat    = (const float*)d_in[2];
    const float* offsets = (const float*)d_in[3];
    float*       out     = (float*)d_out;

    const int batch    = in_sizes[0] / N_LATENT;            // 65536
    const int n_sample = in_sizes[2] / (N_LATENT * N_OUT);  // 1000

    decoder_kernel<<<n_sample * SPLIT, 256, 0, stream>>>(
        u, sid, amat, offsets, out, batch);
}